// Round 10
// baseline (106.685 us; speedup 1.0000x reference)
//
#include <hip/hip_runtime.h>

#define BB    32
#define CINc  64
#define HHc   32
#define WWc   32
#define COc   64
#define KSc   7
#define GGc   8
#define PADc  3
#define CPGc  8
#define NPIX  (HHc * WWc)      // 1024
#define TILEH 8
#define HALOH (TILEH + 6)      // 14
#define HALOW (WWc + 6)        // 38
#define NPOS  (HALOH * HALOW)  // 532

typedef _Float16 half2v __attribute__((ext_vector_type(2)));

#if defined(__has_builtin)
#if __has_builtin(__builtin_amdgcn_fdot2)
#define HAVE_FDOT2 1
#endif
#endif

// TILEH=8 / 256-thread blocks -> 1024 blocks (4+/CU resident) for phase overlap.
// LDS: k-plane f16-packed (8 ch = one float4 of half2s), v in two f32 float4
// planes. 25 KB/block -> 6 blocks/CU capacity. Scores via v_dot2_f32_f16.
// XCD swizzle keeps all 32 blocks of a batch image on one XCD (FETCH 25->4.5MB).
__global__ __launch_bounds__(256, 6) void fused_kernel(
    const float* __restrict__ x,      // [B][64][32][32]
    const float* __restrict__ wq,     // [64][64]
    const float* __restrict__ wk,
    const float* __restrict__ wv,
    const float* __restrict__ rel_h,  // [32][7]
    const float* __restrict__ rel_w,  // [32][7]
    const float* __restrict__ cv,     // [8]
    float* __restrict__ out)          // [B][64][32][32]
{
    __shared__ __attribute__((aligned(16))) float4 kpl[NPOS];   // k[0:8] as 4x half2
    __shared__ __attribute__((aligned(16))) float4 vpl0[NPOS];  // v[0:4] f32
    __shared__ __attribute__((aligned(16))) float4 vpl1[NPOS];  // v[4:8] f32

    // XCD swizzle: all 32 blocks of image b satisfy blockIdx ≡ const (mod 8)
    const int bi   = blockIdx.x;
    const int xcd  = bi & 7;
    const int sIdx = bi >> 3;            // 0..127
    const int im   = sIdx >> 5;          // 0..3 image-within-XCD
    const int j    = sIdx & 31;          // 32 blocks per image
    const int b    = im * 8 + xcd;
    const int g    = j >> 2;
    const int tile = j & 3;
    const int o0   = g * CPGc;
    const int tid  = threadIdx.x;

    const int y0  = tile * TILEH - PADc;             // first halo row (global y)
    const int yv0 = (y0 < 0) ? 0 : y0;               // first valid global y
    const int yv1 = (y0 + HALOH - 1 > HHc - 1) ? (HHc - 1) : (y0 + HALOH - 1);
    const int nvp = ((yv1 - yv0) + 1) << 5;          // valid positions (rows*32)
    const int r0  = yv0 - y0;                        // halo row of first valid row
    const float* xb = x + (size_t)b * CINc * NPIX;

    // ---------- zero-fill all positions (staging overwrites valid ones) ----------
    {
        const float4 z = {0.f, 0.f, 0.f, 0.f};
        for (int p = tid; p < NPOS; p += 256) {
            kpl[p] = z; vpl0[p] = z; vpl1[p] = z;
        }
    }
    __syncthreads();

    // ---------- stage k,v for valid positions (chunked xv[8], proven no-spill) ----------
#pragma unroll 1
    for (int i = tid; i < nvp; i += 256) {
        const int row = i >> 5;
        const int xx  = i & 31;
        const int y   = yv0 + row;
        const float* xp = xb + y * WWc + xx;

        float ak[CPGc], av[CPGc];
#pragma unroll
        for (int oi = 0; oi < CPGc; ++oi) { ak[oi] = 0.f; av[oi] = 0.f; }

        for (int c0 = 0; c0 < CINc; c0 += 8) {
            float xv[8];
#pragma unroll
            for (int jj = 0; jj < 8; ++jj)
                xv[jj] = xp[(c0 + jj) * NPIX];
#pragma unroll
            for (int oi = 0; oi < CPGc; ++oi) {
                const float* wkr = wk + (o0 + oi) * CINc + c0;  // uniform -> s_load
                const float* wvr = wv + (o0 + oi) * CINc + c0;
#pragma unroll
                for (int jj = 0; jj < 8; ++jj) {
                    ak[oi] = fmaf(xv[jj], wkr[jj], ak[oi]);
                    av[oi] = fmaf(xv[jj], wvr[jj], av[oi]);
                }
            }
        }

        const int p = (r0 + row) * HALOW + (xx + PADc);
        float4 kst;
        half2v* kp = (half2v*)&kst;
#pragma unroll
        for (int jj = 0; jj < 4; ++jj)
            kp[jj] = half2v{(_Float16)ak[2 * jj], (_Float16)ak[2 * jj + 1]};
        kpl[p]  = kst;
        vpl0[p] = (float4){av[0], av[1], av[2], av[3]};
        vpl1[p] = (float4){av[4], av[5], av[6], av[7]};
    }

    // ---------- q for own pixel (chunked) ----------
    const int w  = tid & 31;
    const int lh = tid >> 5;               // 0..7
    const int h  = tile * TILEH + lh;
    const int poff = h * WWc + w;

    float q[CPGc];
#pragma unroll
    for (int oi = 0; oi < CPGc; ++oi) q[oi] = 0.f;

    for (int c0 = 0; c0 < CINc; c0 += 8) {
        float xv[8];
#pragma unroll
        for (int jj = 0; jj < 8; ++jj)
            xv[jj] = xb[(c0 + jj) * NPIX + poff];
#pragma unroll
        for (int oi = 0; oi < CPGc; ++oi) {
            const float* wqr = wq + (o0 + oi) * CINc + c0;      // uniform -> s_load
#pragma unroll
            for (int jj = 0; jj < 8; ++jj)
                q[oi] = fmaf(xv[jj], wqr[jj], q[oi]);
        }
    }

#if HAVE_FDOT2
    half2v q2[4];
#pragma unroll
    for (int jj = 0; jj < 4; ++jj)
        q2[jj] = half2v{(_Float16)q[2 * jj], (_Float16)q[2 * jj + 1]};
#endif

    // qrel[t] = sum_oi q[oi] * rel[oi][t]
    const bool use_h = (g < 4);
    const float* relp = use_h ? (rel_h + o0 * KSc) : (rel_w + (o0 - 32) * KSc);
    float qrel[KSc];
#pragma unroll
    for (int tt = 0; tt < KSc; ++tt) {
        float s = 0.f;
#pragma unroll
        for (int oi = 0; oi < CPGc; ++oi)
            s = fmaf(q[oi], relp[oi * KSc + tt], s);
        qrel[tt] = s;
    }

    __syncthreads();

    // ---------- taps: score -> exp -> den & acc, fully fused per tap ----------
    float den = 0.f;
    float acc[CPGc];
#pragma unroll
    for (int oi = 0; oi < CPGc; ++oi) acc[oi] = 0.f;

#pragma unroll
    for (int ki = 0; ki < KSc; ++ki) {
        const int rbase = (lh + ki) * HALOW + w;
#pragma unroll
        for (int kj = 0; kj < KSc; ++kj) {
            const int p = rbase + kj;
            const float4 kraw = kpl[p];
            const float4 v0   = vpl0[p];
            const float4 v1   = vpl1[p];

            float s = use_h ? qrel[ki] : qrel[kj];
#if HAVE_FDOT2
            const half2v* kh = (const half2v*)&kraw;
            s = __builtin_amdgcn_fdot2(q2[0], kh[0], s, false);
            s = __builtin_amdgcn_fdot2(q2[1], kh[1], s, false);
            s = __builtin_amdgcn_fdot2(q2[2], kh[2], s, false);
            s = __builtin_amdgcn_fdot2(q2[3], kh[3], s, false);
#else
            const half2v* kh = (const half2v*)&kraw;
#pragma unroll
            for (int jj = 0; jj < 4; ++jj) {
                s = fmaf(q[2 * jj],     (float)kh[jj].x, s);
                s = fmaf(q[2 * jj + 1], (float)kh[jj].y, s);
            }
#endif
            const float e = __expf(s);   // |s| stat-bounded << 88: no-max softmax
            den += e;
            acc[0] = fmaf(e, v0.x, acc[0]); acc[1] = fmaf(e, v0.y, acc[1]);
            acc[2] = fmaf(e, v0.z, acc[2]); acc[3] = fmaf(e, v0.w, acc[3]);
            acc[4] = fmaf(e, v1.x, acc[4]); acc[5] = fmaf(e, v1.y, acc[5]);
            acc[6] = fmaf(e, v1.z, acc[6]); acc[7] = fmaf(e, v1.w, acc[7]);
        }
    }

    // ---------- adaptive mask + write ----------
    const int  r  = min(h, HHc - 1 - h);
    const int  lo = (h <= HHc - 1 - h) ? r : r + 1;
    const int  hi = HHc - 1 - r;
    const bool in_ring = (w >= lo) && (w <= hi);
    const float cvg = cv[g];
    float om = ((float)r - 15.0f + cvg * 16.0f) * (1.0f / 3.0f) + 1.0f;
    om = fminf(fmaxf(om, 0.0f), 1.0f);
    const float maskv = in_ring ? om : 1.0f;
    const float scale = maskv / den;

    float* ob = out + ((size_t)b * COc + o0) * NPIX + poff;
#pragma unroll
    for (int oi = 0; oi < CPGc; ++oi)
        ob[(size_t)oi * NPIX] = acc[oi] * scale;
}

extern "C" void kernel_launch(void* const* d_in, const int* in_sizes, int n_in,
                              void* d_out, int out_size, void* d_ws, size_t ws_size,
                              hipStream_t stream) {
    const float* x     = (const float*)d_in[0];
    const float* wq    = (const float*)d_in[1];
    const float* wk    = (const float*)d_in[2];
    const float* wv    = (const float*)d_in[3];
    const float* rel_h = (const float*)d_in[4];
    const float* rel_w = (const float*)d_in[5];
    const float* cv    = (const float*)d_in[6];
    float* out = (float*)d_out;

    fused_kernel<<<1024, 256, 0, stream>>>(x, wq, wk, wv, rel_h, rel_w, cv, out);
}